// Round 4
// baseline (249.234 us; speedup 1.0000x reference)
//
#include <hip/hip_runtime.h>
#include <stdint.h>

// GraphCut fused contrastive loss, MI355X (gfx950) — round 4.
// loss = -mean_i( sum_{j!=i} sign_ij * exp(sim_ij - rowmax_i) ), sim = (F F^T)/0.2.
// R3 lesson: per-wave direct B loads -> serial load->MFMA->branch chain, latency
// never hidden (47 us, no pipe >26%). Fix (m97 pattern): double-buffered LDS
// staging via global_load_lds width=16 -- next tile's stage is in flight across
// this tile's compute. 2 A-tiles per wave so each B fragment feeds 2 MFMAs
// (halves LDS read traffic; MFMA becomes the binding pipe ~6.8 us/CU).

#define M_ROWS 8192
#define K_DIM  128
#define NCHUNK 16
#define CHUNK_COLS (M_ROWS / NCHUNK)      // 512
#define NT_PER_CHUNK (CHUNK_COLS / 32)    // 16
#define TILE_BYTES 8192                   // one 32-col B tile: 512 granules x 16 B
#define INV_T_LOG2E 7.213475204444817f    // (1/0.2) * log2(e)

typedef __bf16 bf16x8 __attribute__((ext_vector_type(8)));
typedef float  f32x16 __attribute__((ext_vector_type(16)));
typedef unsigned short ushort8v __attribute__((ext_vector_type(8)));

// FB fragment layout: 16-B granule index = (ct*16 + s8*2 + l5)*32 + lm,
// holding bf16 F[ct*32 + lm][16*s8 + 8*l5 + e], e = 0..7.

// ---- prep: fp32 -> bf16 (RNE) into fragment layout + per-row self-dot ----
__global__ __launch_bounds__(256) void prep_kernel(const float* __restrict__ f,
                                                   ushort8v* __restrict__ FB,
                                                   float* __restrict__ selfdot,
                                                   float* __restrict__ out) {
    const int t    = threadIdx.x;
    const int row  = blockIdx.x * 16 + (t >> 4);
    const int slot = t & 15;                      // = s8*2 + l5
    const float4 v0 = *(const float4*)(f + (size_t)row * K_DIM + slot * 8);
    const float4 v1 = *(const float4*)(f + (size_t)row * K_DIM + slot * 8 + 4);
    float x[8] = {v0.x, v0.y, v0.z, v0.w, v1.x, v1.y, v1.z, v1.w};
    ushort8v h;
    float ss = 0.f;
#pragma unroll
    for (int e = 0; e < 8; ++e) {
        uint32_t u = __builtin_bit_cast(uint32_t, x[e]);
        uint32_t r = (u + 0x7FFFu + ((u >> 16) & 1u)) >> 16;   // RNE to bf16
        h[e] = (unsigned short)r;
        float b = __builtin_bit_cast(float, r << 16);
        ss += b * b;
    }
#pragma unroll
    for (int off = 1; off < 16; off <<= 1) ss += __shfl_xor(ss, off, 64);
    if (slot == 0) selfdot[row] = ss;
    const int ct = row >> 5, lm = row & 31;
    FB[(size_t)(ct * 16 + slot) * 32 + lm] = h;
    if (blockIdx.x == 0 && t == 0) out[0] = 0.f;   // d_out is poisoned 0xAA
}

// async 16-B global->LDS copy (per-lane src addr; LDS dst = uniform base + lane*16)
__device__ __forceinline__ void async_cp16(const void* src, void* lds_dst) {
    __builtin_amdgcn_global_load_lds(
        (const __attribute__((address_space(1))) unsigned int*)src,
        (__attribute__((address_space(3))) unsigned int*)lds_dst, 16, 0, 0);
}

// ---- main fused kernel: 512 blocks = 32 row-groups(256 rows) x 16 chunks ----
// Block = 4 waves; wave owns 64 rows (2 A-tiles); B tiles staged to LDS,
// double-buffered, shared by all 4 waves.
__global__ void fused_kernel(const ushort8v* __restrict__ FB,
                             const int* __restrict__ labels,
                             const float* __restrict__ selfdot,
                             float* __restrict__ partials) {
    __shared__ char lds[2 * TILE_BYTES];
    const int blk  = blockIdx.x;
    const int rg   = blk >> 4;          // row group (256 rows)
    const int ch   = blk & 15;          // col chunk (512 cols)
    const int tid  = threadIdx.x;
    const int w    = tid >> 6;
    const int lane = tid & 63;
    const int lm   = lane & 31;
    const int l5   = lane >> 5;
    const int row0 = rg * 256 + w * 64;
    const int ct0  = row0 >> 5;

    // resident A fragments: 2 tiles x 8 k-slices (coalesced 1-KB wave loads)
    bf16x8 af[2][8];
#pragma unroll
    for (int tt = 0; tt < 2; ++tt)
#pragma unroll
        for (int s8 = 0; s8 < 8; ++s8)
            af[tt][s8] = (const bf16x8&)FB[(size_t)((ct0 + tt) * 16 + s8 * 2 + l5) * 32 + lm];

    // online-softmax state per owned C-row (C/D layout: row = (r&3)+8*(r>>2)+4*l5)
    float m[2][16], s[2][16];
    float minm = 1e30f;
#pragma unroll
    for (int tt = 0; tt < 2; ++tt)
#pragma unroll
        for (int r = 0; r < 16; ++r) {
            m[tt][r] = selfdot[row0 + tt * 32 + (r & 3) + 8 * (r >> 2) + 4 * l5];
            s[tt][r] = 0.f;
            minm = fminf(minm, m[tt][r]);
        }

    const int ctb0 = ch * NT_PER_CHUNK;
    const char* FBb = (const char*)FB;

    // stage tile 0 into buffer 0: 256 threads x 2 rounds x 16 B = 8 KB
#pragma unroll
    for (int r = 0; r < 2; ++r)
        async_cp16(FBb + (size_t)ctb0 * TILE_BYTES + r * 4096 + tid * 16,
                   lds + r * 4096 + w * 1024);

    for (int nt = 0; nt < NT_PER_CHUNK; ++nt) {
        const int cur = nt & 1;
        __syncthreads();   // stage of buf[cur] landed (vmcnt drained); prior reads of other buf done
        if (nt + 1 < NT_PER_CHUNK) {
#pragma unroll
            for (int r = 0; r < 2; ++r)
                async_cp16(FBb + (size_t)(ctb0 + nt + 1) * TILE_BYTES + r * 4096 + tid * 16,
                           lds + (cur ^ 1) * TILE_BYTES + r * 4096 + w * 1024);
        }

        const char* buf = lds + cur * TILE_BYTES;
        bf16x8 bf[8];
#pragma unroll
        for (int s8 = 0; s8 < 8; ++s8)
            bf[s8] = *(const bf16x8*)(buf + s8 * 1024 + lane * 16);   // ds_read_b128

        f32x16 a0 = {}, a1 = {};
#pragma unroll
        for (int s8 = 0; s8 < 8; ++s8) {
            a0 = __builtin_amdgcn_mfma_f32_32x32x16_bf16(af[0][s8], bf[s8], a0, 0, 0, 0);
            a1 = __builtin_amdgcn_mfma_f32_32x32x16_bf16(af[1][s8], bf[s8], a1, 0, 0, 0);
        }

        float amax = a0[0];
#pragma unroll
        for (int r = 1; r < 16; ++r) amax = fmaxf(amax, a0[r]);
#pragma unroll
        for (int r = 0; r < 16; ++r) amax = fmaxf(amax, a1[r]);
        // wave-uniform skip: exp((acc-m)/T) == 0 in fp32 when acc - m < -21
        if (__any(amax > minm - 22.f)) {
            const int jcol = (ctb0 + nt) * 32 + lm;
            const int labj = labels[jcol];
#pragma unroll
            for (int tt = 0; tt < 2; ++tt)
#pragma unroll
                for (int r = 0; r < 16; ++r) {
                    const int grow = row0 + tt * 32 + (r & 3) + 8 * (r >> 2) + 4 * l5;
                    const float acc = tt ? a1[r] : a0[r];
                    float d    = acc - m[tt][r];
                    float sign = (labj == labels[grow]) ? 1.f : -1.f;
                    if (jcol == grow) sign = 0.f;              // mask diagonal
                    bool  p = d > 0.f;
                    float e = exp2f(fminf(d, -d) * INV_T_LOG2E);
                    float xx = p ? s[tt][r] : sign;
                    float yy = p ? sign : s[tt][r];
                    s[tt][r] = fmaf(xx, e, yy);                // online rescale-or-add
                    m[tt][r] = fmaxf(m[tt][r], acc);
                }
            minm = m[0][0];
#pragma unroll
            for (int tt = 0; tt < 2; ++tt)
#pragma unroll
                for (int r = 0; r < 16; ++r) minm = fminf(minm, m[tt][r]);
        }
    }

    // merge the 32 column-lane partials of each row (offs stay within l5 half)
#pragma unroll
    for (int off = 1; off < 32; off <<= 1) {
#pragma unroll
        for (int tt = 0; tt < 2; ++tt)
#pragma unroll
            for (int r = 0; r < 16; ++r) {
                float mo = __shfl_xor(m[tt][r], off, 64);
                float so = __shfl_xor(s[tt][r], off, 64);
                float d  = mo - m[tt][r];
                bool  p  = d > 0.f;
                float e  = exp2f(fminf(d, -d) * INV_T_LOG2E);
                s[tt][r] = p ? fmaf(s[tt][r], e, so) : fmaf(so, e, s[tt][r]);
                m[tt][r] = fmaxf(m[tt][r], mo);
            }
    }
    if (lm == 0) {
#pragma unroll
        for (int tt = 0; tt < 2; ++tt)
#pragma unroll
            for (int r = 0; r < 16; ++r) {
                const int grow = row0 + tt * 32 + (r & 3) + 8 * (r >> 2) + 4 * l5;
                float* p = partials + ((size_t)grow * NCHUNK + ch) * 2;
                p[0] = m[tt][r];
                p[1] = s[tt][r];
            }
    }
}

// ---- merge 16 chunk-partials per row, reduce, atomic add ----
__global__ __launch_bounds__(256) void merge_kernel(const float* __restrict__ partials,
                                                    float* __restrict__ out) {
    const int g = blockIdx.x * 256 + threadIdx.x;    // row id
    float M = -1e30f, S = 0.f;
#pragma unroll
    for (int c = 0; c < NCHUNK; ++c) {
        const float* p = partials + ((size_t)g * NCHUNK + c) * 2;
        float mo = p[0], so = p[1];
        float d  = mo - M;
        bool  pr = d > 0.f;
        float e  = exp2f(fminf(d, -d) * INV_T_LOG2E);
        S = pr ? fmaf(S, e, so) : fmaf(so, e, S);
        M = fmaxf(M, mo);
    }
    float val = -S * (1.0f / 8192.0f);
#pragma unroll
    for (int off = 1; off < 64; off <<= 1) val += __shfl_xor(val, off, 64);
    __shared__ float red[4];
    if ((threadIdx.x & 63) == 0) red[threadIdx.x >> 6] = val;
    __syncthreads();
    if (threadIdx.x == 0) atomicAdd(out, red[0] + red[1] + red[2] + red[3]);
}

extern "C" void kernel_launch(void* const* d_in, const int* in_sizes, int n_in,
                              void* d_out, int out_size, void* d_ws, size_t ws_size,
                              hipStream_t stream) {
    const float* feat   = (const float*)d_in[0];
    const int*   labels = (const int*)d_in[1];
    float*       out    = (float*)d_out;
    char*        ws     = (char*)d_ws;

    ushort8v* FB       = (ushort8v*)ws;                                          // 2 MB
    float*    selfdot  = (float*)(ws + (size_t)M_ROWS * K_DIM * 2);              // 32 KB
    float*    partials = (float*)(ws + (size_t)M_ROWS * K_DIM * 2 + M_ROWS * 4); // 1 MB

    prep_kernel<<<M_ROWS / 16, 256, 0, stream>>>(feat, FB, selfdot, out);
    fused_kernel<<<(M_ROWS / 256) * NCHUNK, 256, 0, stream>>>(FB, labels, selfdot, partials);
    merge_kernel<<<M_ROWS / 256, 256, 0, stream>>>(partials, out);
}

// Round 5
// 136.987 us; speedup vs baseline: 1.8194x; 1.8194x over previous
//
#include <hip/hip_runtime.h>
#include <stdint.h>

// GraphCut fused contrastive loss, MI355X (gfx950) — round 5.
// loss = -mean_i( sum_{j!=i} sign_ij * exp(sim_ij - rowmax_i) ), sim = (F F^T)/0.2.
// R4 lesson: fused_kernel without __launch_bounds__ defaults to a 1024-thread
// cap -> 64 VGPRs -> 140+ MB spill traffic (194 us, MfmaUtil 0.05%). This
// round: identical structure + __launch_bounds__(256) (no min-waves arg --
// that caused R2's cap-to-128 spills). Double-buffered LDS staging via
// global_load_lds w=16; 2 A-tiles/wave so each staged B fragment feeds 2 MFMAs.

#define M_ROWS 8192
#define K_DIM  128
#define NCHUNK 16
#define CHUNK_COLS (M_ROWS / NCHUNK)      // 512
#define NT_PER_CHUNK (CHUNK_COLS / 32)    // 16
#define TILE_BYTES 8192                   // one 32-col B tile: 512 granules x 16 B
#define INV_T_LOG2E 7.213475204444817f    // (1/0.2) * log2(e)

typedef __bf16 bf16x8 __attribute__((ext_vector_type(8)));
typedef float  f32x16 __attribute__((ext_vector_type(16)));
typedef unsigned short ushort8v __attribute__((ext_vector_type(8)));

// FB fragment layout: 16-B granule index = (ct*16 + s8*2 + l5)*32 + lm,
// holding bf16 F[ct*32 + lm][16*s8 + 8*l5 + e], e = 0..7.

// ---- prep: fp32 -> bf16 (RNE) into fragment layout + per-row self-dot ----
__global__ __launch_bounds__(256) void prep_kernel(const float* __restrict__ f,
                                                   ushort8v* __restrict__ FB,
                                                   float* __restrict__ selfdot,
                                                   float* __restrict__ out) {
    const int t    = threadIdx.x;
    const int row  = blockIdx.x * 16 + (t >> 4);
    const int slot = t & 15;                      // = s8*2 + l5
    const float4 v0 = *(const float4*)(f + (size_t)row * K_DIM + slot * 8);
    const float4 v1 = *(const float4*)(f + (size_t)row * K_DIM + slot * 8 + 4);
    float x[8] = {v0.x, v0.y, v0.z, v0.w, v1.x, v1.y, v1.z, v1.w};
    ushort8v h;
    float ss = 0.f;
#pragma unroll
    for (int e = 0; e < 8; ++e) {
        uint32_t u = __builtin_bit_cast(uint32_t, x[e]);
        uint32_t r = (u + 0x7FFFu + ((u >> 16) & 1u)) >> 16;   // RNE to bf16
        h[e] = (unsigned short)r;
        float b = __builtin_bit_cast(float, r << 16);
        ss += b * b;
    }
#pragma unroll
    for (int off = 1; off < 16; off <<= 1) ss += __shfl_xor(ss, off, 64);
    if (slot == 0) selfdot[row] = ss;
    const int ct = row >> 5, lm = row & 31;
    FB[(size_t)(ct * 16 + slot) * 32 + lm] = h;
    if (blockIdx.x == 0 && t == 0) out[0] = 0.f;   // d_out is poisoned 0xAA
}

// async 16-B global->LDS copy (per-lane src addr; LDS dst = uniform base + lane*16)
__device__ __forceinline__ void async_cp16(const void* src, void* lds_dst) {
    __builtin_amdgcn_global_load_lds(
        (const __attribute__((address_space(1))) unsigned int*)src,
        (__attribute__((address_space(3))) unsigned int*)lds_dst, 16, 0, 0);
}

// ---- main fused kernel: 512 blocks = 32 row-groups(256 rows) x 16 chunks ----
// Block = 4 waves; wave owns 64 rows (2 A-tiles); B tiles staged to LDS,
// double-buffered, shared by all 4 waves.
__global__ __launch_bounds__(256) void fused_kernel(const ushort8v* __restrict__ FB,
                                                    const int* __restrict__ labels,
                                                    const float* __restrict__ selfdot,
                                                    float* __restrict__ partials) {
    __shared__ char lds[2 * TILE_BYTES];
    const int blk  = blockIdx.x;
    const int rg   = blk >> 4;          // row group (256 rows)
    const int ch   = blk & 15;          // col chunk (512 cols)
    const int tid  = threadIdx.x;
    const int w    = tid >> 6;
    const int lane = tid & 63;
    const int lm   = lane & 31;
    const int l5   = lane >> 5;
    const int row0 = rg * 256 + w * 64;
    const int ct0  = row0 >> 5;

    // resident A fragments: 2 tiles x 8 k-slices (coalesced 1-KB wave loads)
    bf16x8 af[2][8];
#pragma unroll
    for (int tt = 0; tt < 2; ++tt)
#pragma unroll
        for (int s8 = 0; s8 < 8; ++s8)
            af[tt][s8] = (const bf16x8&)FB[(size_t)((ct0 + tt) * 16 + s8 * 2 + l5) * 32 + lm];

    // online-softmax state per owned C-row (C/D layout: row = (r&3)+8*(r>>2)+4*l5)
    float m[2][16], s[2][16];
    float minm = 1e30f;
#pragma unroll
    for (int tt = 0; tt < 2; ++tt)
#pragma unroll
        for (int r = 0; r < 16; ++r) {
            m[tt][r] = selfdot[row0 + tt * 32 + (r & 3) + 8 * (r >> 2) + 4 * l5];
            s[tt][r] = 0.f;
            minm = fminf(minm, m[tt][r]);
        }

    const int ctb0 = ch * NT_PER_CHUNK;
    const char* FBb = (const char*)FB;

    // stage tile 0 into buffer 0: 256 threads x 2 rounds x 16 B = 8 KB
#pragma unroll
    for (int r = 0; r < 2; ++r)
        async_cp16(FBb + (size_t)ctb0 * TILE_BYTES + r * 4096 + tid * 16,
                   lds + r * 4096 + w * 1024);

    for (int nt = 0; nt < NT_PER_CHUNK; ++nt) {
        const int cur = nt & 1;
        __syncthreads();   // stage of buf[cur] landed; prior reads of other buf done
        if (nt + 1 < NT_PER_CHUNK) {
#pragma unroll
            for (int r = 0; r < 2; ++r)
                async_cp16(FBb + (size_t)(ctb0 + nt + 1) * TILE_BYTES + r * 4096 + tid * 16,
                           lds + (cur ^ 1) * TILE_BYTES + r * 4096 + w * 1024);
        }

        const char* buf = lds + cur * TILE_BYTES;
        bf16x8 bf[8];
#pragma unroll
        for (int s8 = 0; s8 < 8; ++s8)
            bf[s8] = *(const bf16x8*)(buf + s8 * 1024 + lane * 16);   // ds_read_b128

        f32x16 a0 = {}, a1 = {};
#pragma unroll
        for (int s8 = 0; s8 < 8; ++s8) {
            a0 = __builtin_amdgcn_mfma_f32_32x32x16_bf16(af[0][s8], bf[s8], a0, 0, 0, 0);
            a1 = __builtin_amdgcn_mfma_f32_32x32x16_bf16(af[1][s8], bf[s8], a1, 0, 0, 0);
        }

        float amax = a0[0];
#pragma unroll
        for (int r = 1; r < 16; ++r) amax = fmaxf(amax, a0[r]);
#pragma unroll
        for (int r = 0; r < 16; ++r) amax = fmaxf(amax, a1[r]);
        // wave-uniform skip: exp((acc-m)/T) == 0 in fp32 when acc - m < -21
        if (__any(amax > minm - 22.f)) {
            const int jcol = (ctb0 + nt) * 32 + lm;
            const int labj = labels[jcol];
#pragma unroll
            for (int tt = 0; tt < 2; ++tt)
#pragma unroll
                for (int r = 0; r < 16; ++r) {
                    const int grow = row0 + tt * 32 + (r & 3) + 8 * (r >> 2) + 4 * l5;
                    const float acc = tt ? a1[r] : a0[r];
                    float d    = acc - m[tt][r];
                    float sign = (labj == labels[grow]) ? 1.f : -1.f;
                    if (jcol == grow) sign = 0.f;              // mask diagonal
                    bool  p = d > 0.f;
                    float e = exp2f(fminf(d, -d) * INV_T_LOG2E);
                    float xx = p ? s[tt][r] : sign;
                    float yy = p ? sign : s[tt][r];
                    s[tt][r] = fmaf(xx, e, yy);                // online rescale-or-add
                    m[tt][r] = fmaxf(m[tt][r], acc);
                }
            minm = m[0][0];
#pragma unroll
            for (int tt = 0; tt < 2; ++tt)
#pragma unroll
                for (int r = 0; r < 16; ++r) minm = fminf(minm, m[tt][r]);
        }
    }

    // merge the 32 column-lane partials of each row (offs stay within l5 half)
#pragma unroll
    for (int off = 1; off < 32; off <<= 1) {
#pragma unroll
        for (int tt = 0; tt < 2; ++tt)
#pragma unroll
            for (int r = 0; r < 16; ++r) {
                float mo = __shfl_xor(m[tt][r], off, 64);
                float so = __shfl_xor(s[tt][r], off, 64);
                float d  = mo - m[tt][r];
                bool  p  = d > 0.f;
                float e  = exp2f(fminf(d, -d) * INV_T_LOG2E);
                s[tt][r] = p ? fmaf(s[tt][r], e, so) : fmaf(so, e, s[tt][r]);
                m[tt][r] = fmaxf(m[tt][r], mo);
            }
    }
    if (lm == 0) {
#pragma unroll
        for (int tt = 0; tt < 2; ++tt)
#pragma unroll
            for (int r = 0; r < 16; ++r) {
                const int grow = row0 + tt * 32 + (r & 3) + 8 * (r >> 2) + 4 * l5;
                float* p = partials + ((size_t)grow * NCHUNK + ch) * 2;
                p[0] = m[tt][r];
                p[1] = s[tt][r];
            }
    }
}

// ---- merge 16 chunk-partials per row, reduce, atomic add ----
__global__ __launch_bounds__(256) void merge_kernel(const float* __restrict__ partials,
                                                    float* __restrict__ out) {
    const int g = blockIdx.x * 256 + threadIdx.x;    // row id
    float M = -1e30f, S = 0.f;
#pragma unroll
    for (int c = 0; c < NCHUNK; ++c) {
        const float* p = partials + ((size_t)g * NCHUNK + c) * 2;
        float mo = p[0], so = p[1];
        float d  = mo - M;
        bool  pr = d > 0.f;
        float e  = exp2f(fminf(d, -d) * INV_T_LOG2E);
        S = pr ? fmaf(S, e, so) : fmaf(so, e, S);
        M = fmaxf(M, mo);
    }
    float val = -S * (1.0f / 8192.0f);
#pragma unroll
    for (int off = 1; off < 64; off <<= 1) val += __shfl_xor(val, off, 64);
    __shared__ float red[4];
    if ((threadIdx.x & 63) == 0) red[threadIdx.x >> 6] = val;
    __syncthreads();
    if (threadIdx.x == 0) atomicAdd(out, red[0] + red[1] + red[2] + red[3]);
}

extern "C" void kernel_launch(void* const* d_in, const int* in_sizes, int n_in,
                              void* d_out, int out_size, void* d_ws, size_t ws_size,
                              hipStream_t stream) {
    const float* feat   = (const float*)d_in[0];
    const int*   labels = (const int*)d_in[1];
    float*       out    = (float*)d_out;
    char*        ws     = (char*)d_ws;

    ushort8v* FB       = (ushort8v*)ws;                                          // 2 MB
    float*    selfdot  = (float*)(ws + (size_t)M_ROWS * K_DIM * 2);              // 32 KB
    float*    partials = (float*)(ws + (size_t)M_ROWS * K_DIM * 2 + M_ROWS * 4); // 1 MB

    prep_kernel<<<M_ROWS / 16, 256, 0, stream>>>(feat, FB, selfdot, out);
    fused_kernel<<<(M_ROWS / 256) * NCHUNK, 256, 0, stream>>>(FB, labels, selfdot, partials);
    merge_kernel<<<M_ROWS / 256, 256, 0, stream>>>(partials, out);
}

// Round 6
// 88.114 us; speedup vs baseline: 2.8285x; 1.5546x over previous
//
#include <hip/hip_runtime.h>
#include <stdint.h>

// GraphCut fused contrastive loss, MI355X (gfx950) — round 6.
// loss = -mean_i( sum_{j!=i} sign_ij * exp(sim_ij - rowmax_i) ), sim = (F F^T)/0.2.
// R3 (47us): serial load->MFMA chain, latency-bound, but best so far (12 waves/CU).
// R5 (82us): LDS double-buffer halved occupancy (VGPR 176) and barrier lock-step
//            serialized the block -- worse.
// R6: register software-pipeline on the R3 structure. Two B register buffers;
// tile nt+1's coalesced loads fly during tile nt's MFMA chain (fine-grained
// vmcnt waits, no barriers, no LDS). NCHUNK=8 -> 512 blocks = exactly 2
// blocks/CU, zero tail, 32 tiles/block (2x prologue amortization).

#define M_ROWS 8192
#define K_DIM  128
#define NCHUNK 8
#define CHUNK_COLS (M_ROWS / NCHUNK)      // 1024
#define NT_PER_CHUNK (CHUNK_COLS / 32)    // 32
#define INV_T_LOG2E 7.213475204444817f    // (1/0.2) * log2(e)

typedef __bf16 bf16x8 __attribute__((ext_vector_type(8)));
typedef float  f32x16 __attribute__((ext_vector_type(16)));
typedef unsigned short ushort8v __attribute__((ext_vector_type(8)));

// FB fragment layout: 16-B granule index = (ct*16 + s8*2 + l5)*32 + lm,
// holding bf16 F[ct*32 + lm][16*s8 + 8*l5 + e], e = 0..7. A wave's fragment
// load (lane = l5*32+lm) is 64 consecutive granules = 1 KB contiguous.

// ---- prep: fp32 -> bf16 (RNE) into fragment layout + per-row self-dot ----
__global__ __launch_bounds__(256) void prep_kernel(const float* __restrict__ f,
                                                   ushort8v* __restrict__ FB,
                                                   float* __restrict__ selfdot,
                                                   float* __restrict__ out) {
    const int t    = threadIdx.x;
    const int row  = blockIdx.x * 16 + (t >> 4);
    const int slot = t & 15;                      // = s8*2 + l5
    const float4 v0 = *(const float4*)(f + (size_t)row * K_DIM + slot * 8);
    const float4 v1 = *(const float4*)(f + (size_t)row * K_DIM + slot * 8 + 4);
    float x[8] = {v0.x, v0.y, v0.z, v0.w, v1.x, v1.y, v1.z, v1.w};
    ushort8v h;
    float ss = 0.f;
#pragma unroll
    for (int e = 0; e < 8; ++e) {
        uint32_t u = __builtin_bit_cast(uint32_t, x[e]);
        uint32_t r = (u + 0x7FFFu + ((u >> 16) & 1u)) >> 16;   // RNE to bf16
        h[e] = (unsigned short)r;
        float b = __builtin_bit_cast(float, r << 16);
        ss += b * b;
    }
#pragma unroll
    for (int off = 1; off < 16; off <<= 1) ss += __shfl_xor(ss, off, 64);
    if (slot == 0) selfdot[row] = ss;
    const int ct = row >> 5, lm = row & 31;
    FB[(size_t)(ct * 16 + slot) * 32 + lm] = h;
    if (blockIdx.x == 0 && t == 0) out[0] = 0.f;   // d_out is poisoned 0xAA
}

// ---- main fused kernel: 512 blocks = 64 row-groups(128 rows) x 8 chunks ----
__global__ __launch_bounds__(256) void fused_kernel(const ushort8v* __restrict__ FB,
                                                    const int* __restrict__ labels,
                                                    const float* __restrict__ selfdot,
                                                    float* __restrict__ partials) {
    const int blk  = blockIdx.x;
    const int rg   = blk >> 3;          // row group (128 rows)
    const int ch   = blk & 7;           // col chunk (1024 cols)
    const int w    = threadIdx.x >> 6;
    const int lane = threadIdx.x & 63;
    const int lm   = lane & 31;
    const int l5   = lane >> 5;
    const int row0 = rg * 128 + w * 32;
    const int ct0  = row0 >> 5;

    // resident A fragments (coalesced 1-KB wave loads)
    bf16x8 af[8];
#pragma unroll
    for (int s8 = 0; s8 < 8; ++s8)
        af[s8] = (const bf16x8&)FB[(size_t)(ct0 * 16 + s8 * 2 + l5) * 32 + lm];

    // online-softmax state per owned C-row (C/D layout: row = (r&3)+8*(r>>2)+4*l5)
    float m[16], s[16];
    float minm = 1e30f;
#pragma unroll
    for (int r = 0; r < 16; ++r) {
        m[r] = selfdot[row0 + (r & 3) + 8 * (r >> 2) + 4 * l5];  // diag dot ~ row max
        s[r] = 0.f;
        minm = fminf(minm, m[r]);
    }

    const int ctb0 = ch * NT_PER_CHUNK;

    auto loadB = [&](int nt, bf16x8* dst) {
#pragma unroll
        for (int s8 = 0; s8 < 8; ++s8)
            dst[s8] = (const bf16x8&)FB[(size_t)((ctb0 + nt) * 16 + s8 * 2 + l5) * 32 + lm];
    };

    auto computeTile = [&](int nt, const bf16x8* bf) {
        f32x16 acc = {};
#pragma unroll
        for (int s8 = 0; s8 < 8; ++s8)
            acc = __builtin_amdgcn_mfma_f32_32x32x16_bf16(af[s8], bf[s8], acc, 0, 0, 0);
        float amax = acc[0];
#pragma unroll
        for (int r = 1; r < 16; ++r) amax = fmaxf(amax, acc[r]);
        // wave-uniform skip: exp((acc-m)/T) == 0 in fp32 when acc - m < -21
        if (__any(amax > minm - 22.f)) {
            const int jcol = (ctb0 + nt) * 32 + lm;
            const int labj = labels[jcol];
#pragma unroll
            for (int r = 0; r < 16; ++r) {
                const int grow = row0 + (r & 3) + 8 * (r >> 2) + 4 * l5;
                float d    = acc[r] - m[r];
                float sign = (labj == labels[grow]) ? 1.f : -1.f;
                if (jcol == grow) sign = 0.f;              // mask diagonal
                bool  p = d > 0.f;
                float e = exp2f(fminf(d, -d) * INV_T_LOG2E);
                float xx = p ? s[r] : sign;
                float yy = p ? sign : s[r];
                s[r] = fmaf(xx, e, yy);                    // online rescale-or-add
                m[r] = fmaxf(m[r], acc[r]);
            }
            minm = m[0];
#pragma unroll
            for (int r = 1; r < 16; ++r) minm = fminf(minm, m[r]);
        }
    };

    // software pipeline: while computing tile nt from one buffer, the other
    // buffer's loads are in flight (load-to-use distance = one tile's compute).
    bf16x8 b0[8], b1[8];
    loadB(0, b0);
    for (int nt = 0; nt < NT_PER_CHUNK; nt += 2) {
        loadB(nt + 1, b1);
        computeTile(nt, b0);
        if (nt + 2 < NT_PER_CHUNK) loadB(nt + 2, b0);
        computeTile(nt + 1, b1);
    }

    // merge the 32 column-lane partials of each row (offs stay within l5 half)
#pragma unroll
    for (int off = 1; off < 32; off <<= 1) {
#pragma unroll
        for (int r = 0; r < 16; ++r) {
            float mo = __shfl_xor(m[r], off, 64);
            float so = __shfl_xor(s[r], off, 64);
            float d  = mo - m[r];
            bool  p  = d > 0.f;
            float e  = exp2f(fminf(d, -d) * INV_T_LOG2E);
            s[r] = p ? fmaf(s[r], e, so) : fmaf(so, e, s[r]);
            m[r] = fmaxf(m[r], mo);
        }
    }
    if (lm == 0) {
#pragma unroll
        for (int r = 0; r < 16; ++r) {
            const int grow = row0 + (r & 3) + 8 * (r >> 2) + 4 * l5;
            float* p = partials + ((size_t)grow * NCHUNK + ch) * 2;
            p[0] = m[r];
            p[1] = s[r];
        }
    }
}

// ---- merge chunk-partials per row, reduce, atomic add ----
__global__ __launch_bounds__(256) void merge_kernel(const float* __restrict__ partials,
                                                    float* __restrict__ out) {
    const int g = blockIdx.x * 256 + threadIdx.x;    // row id
    float M = -1e30f, S = 0.f;
#pragma unroll
    for (int c = 0; c < NCHUNK; ++c) {
        const float* p = partials + ((size_t)g * NCHUNK + c) * 2;
        float mo = p[0], so = p[1];
        float d  = mo - M;
        bool  pr = d > 0.f;
        float e  = exp2f(fminf(d, -d) * INV_T_LOG2E);
        S = pr ? fmaf(S, e, so) : fmaf(so, e, S);
        M = fmaxf(M, mo);
    }
    float val = -S * (1.0f / 8192.0f);
#pragma unroll
    for (int off = 1; off < 64; off <<= 1) val += __shfl_xor(val, off, 64);
    __shared__ float red[4];
    if ((threadIdx.x & 63) == 0) red[threadIdx.x >> 6] = val;
    __syncthreads();
    if (threadIdx.x == 0) atomicAdd(out, red[0] + red[1] + red[2] + red[3]);
}

extern "C" void kernel_launch(void* const* d_in, const int* in_sizes, int n_in,
                              void* d_out, int out_size, void* d_ws, size_t ws_size,
                              hipStream_t stream) {
    const float* feat   = (const float*)d_in[0];
    const int*   labels = (const int*)d_in[1];
    float*       out    = (float*)d_out;
    char*        ws     = (char*)d_ws;

    ushort8v* FB       = (ushort8v*)ws;                                          // 2 MB
    float*    selfdot  = (float*)(ws + (size_t)M_ROWS * K_DIM * 2);              // 32 KB
    float*    partials = (float*)(ws + (size_t)M_ROWS * K_DIM * 2 + M_ROWS * 4); // 512 KB

    prep_kernel<<<M_ROWS / 16, 256, 0, stream>>>(feat, FB, selfdot, out);
    fused_kernel<<<(M_ROWS / 128) * NCHUNK, 256, 0, stream>>>(FB, labels, selfdot, partials);
    merge_kernel<<<M_ROWS / 256, 256, 0, stream>>>(partials, out);
}